// Round 1
// baseline (874.802 us; speedup 1.0000x reference)
//
#include <hip/hip_runtime.h>
#include <hip/hip_bf16.h>

#define N_BATCH 8
#define N_CH    16
#define N_SMP   480000
#define N_EARS  2
#define N_TAP   2048

#define NKT     65                    // K-tiles (of 32) per channel
#define KC      (NKT * 32)            // 2080 padded taps per channel
#define ROWS    128                   // q-rows per block (16 samples each)
#define N_QROWS (N_SMP / 16)          // 30000
#define QB_PER_B ((N_QROWS + ROWS - 1) / ROWS)   // 235
#define CH_PER_PHASE 4
#define N_PHASES (N_CH / CH_PER_PHASE)
#define WIN     (16 * ROWS + KC - 16) // 4112 samples of x per channel per block

typedef __bf16 bf16x8 __attribute__((ext_vector_type(8)));
typedef float  f32x4  __attribute__((ext_vector_type(4)));

// ---------------------------------------------------------------------------
// Prep: pack the filters into MFMA-B-fragment order (Toeplitz arrangement).
// B[u][n] = h[e][c][2048 - u + n], u = kt*32 + quad*8 + j, n = lane&15.
// Flat layout: (((c*NKT + kt)*2 + e)*64 + lane)*8 + j   -> 16B per lane, coalesced.
// ---------------------------------------------------------------------------
__global__ void build_bpk(const float* __restrict__ h, __bf16* __restrict__ bpk)
{
    const int idx = blockIdx.x * 256 + threadIdx.x;
    const int total = N_CH * NKT * 2 * 64 * 8;
    if (idx >= total) return;

    const int j    = idx & 7;
    const int lane = (idx >> 3) & 63;
    const int e    = (idx >> 9) & 1;
    const int ckt  = idx >> 10;          // c*NKT + kt
    const int kt   = ckt % NKT;
    const int c    = ckt / NKT;

    const int n  = lane & 15;
    const int kq = (lane >> 4) * 8 + j;
    const int u  = kt * 32 + kq;
    const int k  = 2048 - u + n;

    float val = (k >= 0 && k < N_TAP) ? h[((long)e * N_CH + c) * N_TAP + k] : 0.0f;
    bpk[idx] = (__bf16)val;
}

// ---------------------------------------------------------------------------
// Main GEMM: per block, 128 q-rows (2048 output samples) for one batch b.
// Wave w owns rows [w*32, w*32+32); accumulators: 2 M-subtiles x 2 ears.
// A[q][u] = x[16q - 2048 + u] read from a per-channel LDS window (bf16).
// ---------------------------------------------------------------------------
__global__ __launch_bounds__(256, 4)
void hoa_bin_gemm(const float* __restrict__ hoa,
                  const __bf16* __restrict__ bpk,
                  float* __restrict__ out)
{
    __shared__ __align__(16) __bf16 xs[CH_PER_PHASE][WIN];

    const int qb   = blockIdx.x;          // 0..234
    const int b    = blockIdx.y;          // 0..7
    const int tid  = threadIdx.x;
    const int lane = tid & 63;
    const int wv   = tid >> 6;            // wave 0..3
    const int mlan = lane & 15;
    const int quad = lane >> 4;

    const int q0 = qb * ROWS;             // local q-row base for this block
    const int t0 = 16 * q0 - 2048;        // sample index of xs[.][0] (may be <0)

    f32x4 acc00{}, acc01{}, acc10{}, acc11{};   // [msub][ear]

    for (int ph = 0; ph < N_PHASES; ++ph) {
        __syncthreads();    // previous phase's readers done before overwrite

        // ---- stage 4 channels: fp32 global -> bf16 LDS window ----
        for (int cc = 0; cc < CH_PER_PHASE; ++cc) {
            const int c = ph * CH_PER_PHASE + cc;
            const float* xc = hoa + ((long)(b * N_CH + c)) * N_SMP;
            for (int i = tid; i < WIN / 4; i += 256) {
                const int t = t0 + 4 * i;
                float4 v = {0.f, 0.f, 0.f, 0.f};
                if (t >= 0 && t <= N_SMP - 4) v = *(const float4*)(xc + t);
                union { __bf16 hh[4]; uint2 u; } pk;
                pk.hh[0] = (__bf16)v.x; pk.hh[1] = (__bf16)v.y;
                pk.hh[2] = (__bf16)v.z; pk.hh[3] = (__bf16)v.w;
                *(uint2*)(&xs[cc][4 * i]) = pk.u;
            }
        }
        __syncthreads();

        // ---- compute: 4 channels x 65 K-tiles ----
        const __bf16* bptr  = bpk + (long)ph * CH_PER_PHASE * NKT * 1024 + lane * 8;
        const __bf16* arow0 = &xs[0][0] + (wv * 512 + 16 * mlan + 8 * quad);

        for (int cc = 0; cc < CH_PER_PHASE; ++cc) {
            const __bf16* ap = arow0 + cc * WIN;
            for (int kt = 0; kt < NKT; ++kt) {
                bf16x8 a0 = *(const bf16x8*)(ap + kt * 32);         // rows m..  (msub 0)
                bf16x8 a1 = *(const bf16x8*)(ap + 256 + kt * 32);   // rows m+16 (msub 1)
                bf16x8 b0 = *(const bf16x8*)(bptr);                 // ear 0
                bf16x8 b1 = *(const bf16x8*)(bptr + 512);           // ear 1
                bptr += 1024;
                acc00 = __builtin_amdgcn_mfma_f32_16x16x32_bf16(a0, b0, acc00, 0, 0, 0);
                acc01 = __builtin_amdgcn_mfma_f32_16x16x32_bf16(a0, b1, acc01, 0, 0, 0);
                acc10 = __builtin_amdgcn_mfma_f32_16x16x32_bf16(a1, b0, acc10, 0, 0, 0);
                acc11 = __builtin_amdgcn_mfma_f32_16x16x32_bf16(a1, b1, acc11, 0, 0, 0);
            }
        }
    }

    // ---- epilogue: C/D layout row = quad*4 + r, col = lane&15 ----
    const long obase = (long)b * N_EARS * N_SMP;
    for (int ms = 0; ms < 2; ++ms) {
        for (int e = 0; e < N_EARS; ++e) {
            f32x4 a = (ms == 0) ? (e == 0 ? acc00 : acc01)
                                : (e == 0 ? acc10 : acc11);
            for (int r = 0; r < 4; ++r) {
                const int rl = wv * 32 + ms * 16 + quad * 4 + r;  // row in block
                const int q  = q0 + rl;
                if (q < N_QROWS) {
                    const int t = 16 * q + mlan;
                    out[obase + (long)e * N_SMP + t] = a[r];
                }
            }
        }
    }
}

// ---------------------------------------------------------------------------
extern "C" void kernel_launch(void* const* d_in, const int* in_sizes, int n_in,
                              void* d_out, int out_size, void* d_ws, size_t ws_size,
                              hipStream_t stream)
{
    const float* hoa = (const float*)d_in[0];   // [8,16,480000] fp32
    const float* h   = (const float*)d_in[1];   // [2,16,2048]  fp32
    float* out       = (float*)d_out;           // [8,2,480000] fp32
    __bf16* bpk      = (__bf16*)d_ws;           // 2,129,920 B filter pack

    const int total_bpk = N_CH * NKT * 2 * 64 * 8;          // 1,064,960
    build_bpk<<<(total_bpk + 255) / 256, 256, 0, stream>>>(h, bpk);

    dim3 grid(QB_PER_B, N_BATCH);
    hoa_bin_gemm<<<grid, 256, 0, stream>>>(hoa, bpk, out);
}